// Round 7
// baseline (96.161 us; speedup 1.0000x reference)
//
#include <hip/hip_runtime.h>
#include <hip/hip_bf16.h>

// Problem constants (reference: B=2048, N_BINS=200, D=128, G=100)
#define NB    200
#define BSZ   2048
#define DD    128
#define GG    100
#define WROWS 112                 // padded gene rows (7 frags of 16) in WS image
#define ROWB  256                 // bytes per LDS W row (128 bf16)
#define WIMG  (WROWS * ROWB)      // 28672 B per-bin W image in d_ws
#define WLDS  (100 * ROWB)        // 25600 B staged rows (rows >=100 never stored)
#define SCR   6400                // per-wave epilogue scratch bytes
#define NBLK2 800                 // bin-major grid: block b -> bin b>>2, 4 mtiles

typedef __attribute__((ext_vector_type(8))) short  short8;  // 8 bf16 (MFMA A/B frag)
typedef __attribute__((ext_vector_type(4))) float  f32x4;   // MFMA C/D frag
typedef __attribute__((ext_vector_type(4))) int    i32x4;   // 16B chunk

// round-to-nearest-even f32 -> bf16, two at a time packed into a dword
__device__ __forceinline__ unsigned f2bf_pack(float lo, float hi) {
    unsigned ulo = __builtin_bit_cast(unsigned, lo);
    ulo += 0x7FFFu + ((ulo >> 16) & 1u);
    unsigned uhi = __builtin_bit_cast(unsigned, hi);
    uhi += 0x7FFFu + ((uhi >> 16) & 1u);
    return (ulo >> 16) | (uhi & 0xFFFF0000u);
}

__device__ __forceinline__ void gload_lds16(const void* g, void* l) {
    __builtin_amdgcn_global_load_lds(
        (const __attribute__((address_space(1))) unsigned int*)g,
        (__attribute__((address_space(3))) unsigned int*)l, 16, 0, 0);
}

// Wave-level LDS drain (scratch is wave-private): lgkmcnt(0) only.
#define WAIT_LGKM0() do { asm volatile("" ::: "memory");     \
                          __builtin_amdgcn_s_waitcnt(0xC07F);\
                          __builtin_amdgcn_sched_barrier(0); \
                          __builtin_amdgcn_wave_barrier();   \
                          asm volatile("" ::: "memory"); } while (0)

// ---------------------------------------------------------------------------
// Pre-pass: W f32 [NB][GG][DD] -> bf16 swizzled per-bin images in d_ws.
// byte off = row*256 + ((granule*16) ^ ((row&7)<<4)), rows >= GG zeroed.
// 16 granules of 16 B per row: 200*112*16 = 358400 threads.
// ---------------------------------------------------------------------------
__global__ __launch_bounds__(256) void wconv_kernel(
    const float* __restrict__ W, unsigned char* __restrict__ ws)
{
    const int gidx = blockIdx.x * 256 + threadIdx.x;
    if (gidx >= NB * WROWS * 16) return;
    const int gr  = gidx & 15;
    const int row = (gidx >> 4) % WROWS;
    const int n   = gidx / (WROWS * 16);
    i32x4 pack = (i32x4){0, 0, 0, 0};
    if (row < GG) {
        const float* src = W + ((size_t)n * GG + row) * DD + gr * 8;
        const f32x4 a = *reinterpret_cast<const f32x4*>(src);
        const f32x4 b = *reinterpret_cast<const f32x4*>(src + 4);
        pack.x = (int)f2bf_pack(a[0], a[1]);
        pack.y = (int)f2bf_pack(a[2], a[3]);
        pack.z = (int)f2bf_pack(b[0], b[1]);
        pack.w = (int)f2bf_pack(b[2], b[3]);
    }
    const int off = row * ROWB + ((gr * 16) ^ ((row & 7) << 4));
    *reinterpret_cast<i32x4*>(ws + (size_t)n * WIMG + off) = pack;
}

// ---------------------------------------------------------------------------
// Helpers
// ---------------------------------------------------------------------------
// Stage first 100 rows (25600 B) of bin n's image: 25 wave-chunks of 1024 B.
// Wave w takes chunks {w, w+4, ..}; chunk 24 goes to wave 0 (25 = 6*4 + 1).
__device__ __forceinline__ void stage_w100(char* buf, const unsigned char* WS,
                                           int n, int lane, int wid) {
    const unsigned char* src = WS + (size_t)n * WIMG;
    #pragma unroll
    for (int i = 0; i < 6; ++i) {
        const int c = i * 4 + wid;                    // chunks 0..23
        gload_lds16(src + c * 1024 + lane * 16, buf + c * 1024);
    }
    if (wid == 0)                                     // chunk 24
        gload_lds16(src + 24 * 1024 + lane * 16, buf + 24 * 1024);
}

__device__ __forceinline__ void load_x(f32x4 (&raw)[2][4][2], const float* X,
                                       int n, int mtile, int wid, int l15, int lhi) {
    const int rowbase = mtile * 128 + wid * 32;
    #pragma unroll
    for (int rf = 0; rf < 2; ++rf) {
        const float* xrow = X + ((size_t)(rowbase + rf * 16 + l15) * NB + n) * DD + lhi * 8;
        #pragma unroll
        for (int ks = 0; ks < 4; ++ks) {
            raw[rf][ks][0] = *reinterpret_cast<const f32x4*>(xrow + ks * 32);
            raw[rf][ks][1] = *reinterpret_cast<const f32x4*>(xrow + ks * 32 + 4);
        }
    }
}

__device__ __forceinline__ void conv_x(const f32x4 (&raw)[2][4][2],
                                       short8 (&areg)[2][4]) {
    #pragma unroll
    for (int rf = 0; rf < 2; ++rf)
        #pragma unroll
        for (int ks = 0; ks < 4; ++ks) {
            const f32x4 a = raw[rf][ks][0];
            const f32x4 b = raw[rf][ks][1];
            i32x4 pk;
            pk.x = (int)f2bf_pack(a[0], a[1]);
            pk.y = (int)f2bf_pack(a[2], a[3]);
            pk.z = (int)f2bf_pack(b[0], b[1]);
            pk.w = (int)f2bf_pack(b[2], b[3]);
            areg[rf][ks] = __builtin_bit_cast(short8, pk);
        }
}

// ---------------------------------------------------------------------------
// Bin-major main kernel: block b -> bin n = b>>2, mtiles (b&3)*4 .. +3.
// W staged ONCE (read-only after one __syncthreads); 4-tile loop has NO
// cross-wave barriers: X prefetch ping-pongs in regs (counted vmcnt by
// compiler, stores never drained), scratch hazards are wave-private.
// LDS = 25600 (W) + 4*6400 (scratch) = 51200+25600? -> 54272 B total
// incl. alignment: 3 blocks/CU (12 waves/CU).
// ---------------------------------------------------------------------------
__global__ __launch_bounds__(256, 3) void mtl_heads_bin(
    const float* __restrict__ X, const float* __restrict__ Bias,
    const unsigned char* __restrict__ WS, float* __restrict__ Out)
{
    const int tid  = threadIdx.x;
    const int lane = tid & 63;
    const int wid  = tid >> 6;
    const int l15  = lane & 15;
    const int lhi  = lane >> 4;

    const int n   = blockIdx.x >> 2;
    const int mt0 = (blockIdx.x & 3) * 4;

    __shared__ __align__(16) char smem[WLDS + 4 * SCR];   // 51200... = 51200+0? (25600+25600=51200)

    // prologue: stage W[n] (async), issue first X tile, bias, convert
    stage_w100(smem, WS, n, lane, wid);
    f32x4 raw[2][4][2];
    load_x(raw, X, n, mt0, wid, l15, lhi);
    float bias[7];
    #pragma unroll
    for (int cf = 0; cf < 7; ++cf) {
        const int g = cf * 16 + l15;
        bias[cf] = (g < GG) ? Bias[n * GG + g] : 0.0f;
    }
    short8 areg[2][4];
    conv_x(raw, areg);          // waits X (staging issued earlier -> also done)
    __syncthreads();            // W visible to all waves; only barrier in kernel

    char* scratch = smem + WLDS + wid * SCR;

    for (int mt = 0; mt < 4; ++mt) {
        const int mtile = mt0 + mt;
        // 1. issue next tile's X loads (hide HBM latency under MFMA+epilogue)
        if (mt < 3) load_x(raw, X, n, mtile + 1, wid, l15, lhi);

        // 2. MFMA: 2 row-frags x 7 col-frags x 4 k-steps from read-only W LDS
        f32x4 acc[2][7];
        #pragma unroll
        for (int rf = 0; rf < 2; ++rf)
            #pragma unroll
            for (int cf = 0; cf < 7; ++cf)
                acc[rf][cf] = (f32x4){0.f, 0.f, 0.f, 0.f};

        #pragma unroll
        for (int cf = 0; cf < 7; ++cf) {
            const int g = cf * 16 + l15;
            const int r = (g < GG) ? g : 99;   // clamp: rows >=100 not staged; masked at store
            const int rowb = r * ROWB;
            const int swz  = (r & 7) << 4;
            #pragma unroll
            for (int ks = 0; ks < 4; ++ks) {
                const int off = rowb + (((lhi * 16) + ks * 64) ^ swz);
                const i32x4 braw = *reinterpret_cast<const i32x4*>(smem + off);  // ds_read_b128
                const short8 bfrag = __builtin_bit_cast(short8, braw);
                acc[0][cf] = __builtin_amdgcn_mfma_f32_16x16x32_bf16(areg[0][ks], bfrag, acc[0][cf], 0, 0, 0);
                acc[1][cf] = __builtin_amdgcn_mfma_f32_16x16x32_bf16(areg[1][ks], bfrag, acc[1][cf], 0, 0, 0);
            }
        }

        // 3. epilogue: wave-private transpose -> contiguous NT dwordx4 stores
        const int rowbase = mtile * 128 + wid * 32;
        float* lds_f = reinterpret_cast<float*>(scratch);
        #pragma unroll
        for (int rf = 0; rf < 2; ++rf) {
            #pragma unroll
            for (int cf = 0; cf < 7; ++cf) {
                const int g = cf * 16 + l15;
                if (g < GG) {
                    #pragma unroll
                    for (int j = 0; j < 4; ++j)
                        lds_f[(lhi * 4 + j) * GG + g] = acc[rf][cf][j] + bias[cf];
                }
            }
            WAIT_LGKM0();
            char* dst = (char*)(Out + ((size_t)n * BSZ + rowbase + rf * 16) * GG);
            #pragma unroll
            for (int it = 0; it < 7; ++it) {
                const int c = it * 64 + lane;        // 16B-chunk index, 400 total
                if (c < 400) {
                    const i32x4 v = *reinterpret_cast<const i32x4*>(scratch + c * 16);
                    __builtin_nontemporal_store(v, reinterpret_cast<i32x4*>(dst + c * 16));
                }
            }
            WAIT_LGKM0();   // scratch reads done before rf=1 (or next tile) overwrites
        }

        // 4. convert next tile's X (compiler emits counted vmcnt; stores stay in flight)
        if (mt < 3) conv_x(raw, areg);
    }
}

// ---------------------------------------------------------------------------
// Fallback (no workspace): single-tile kernel, in-kernel W convert.
// ---------------------------------------------------------------------------
__global__ __launch_bounds__(256, 4) void mtl_heads_fallback(
    const float* __restrict__ X, const float* __restrict__ W,
    const float* __restrict__ Bias, float* __restrict__ Out)
{
    const int n     = blockIdx.y;
    const int mtile = blockIdx.x;
    const int tid   = threadIdx.x;
    const int lane  = tid & 63;
    const int wid   = tid >> 6;
    const int l15   = lane & 15;
    const int lhi   = lane >> 4;

    __shared__ __align__(16) char smem[WIMG];

    {
        const int rsub = tid >> 4;
        const int k0   = (tid & 15) * 8;
        #pragma unroll
        for (int it = 0; it < 7; ++it) {
            const int row = it * 16 + rsub;
            i32x4 pack = (i32x4){0, 0, 0, 0};
            if (row < GG) {
                const float* s = W + ((size_t)n * GG + row) * DD + k0;
                const f32x4 a = *reinterpret_cast<const f32x4*>(s);
                const f32x4 b = *reinterpret_cast<const f32x4*>(s + 4);
                pack.x = (int)f2bf_pack(a[0], a[1]);
                pack.y = (int)f2bf_pack(a[2], a[3]);
                pack.z = (int)f2bf_pack(b[0], b[1]);
                pack.w = (int)f2bf_pack(b[2], b[3]);
            }
            const int off = row * ROWB + ((k0 * 2) ^ ((row & 7) << 4));
            *reinterpret_cast<i32x4*>(smem + off) = pack;
        }
    }

    const int rowbase = mtile * 128 + wid * 32;
    f32x4 raw[2][4][2];
    load_x(raw, X, n, mtile, wid, l15, lhi);
    float bias[7];
    #pragma unroll
    for (int cf = 0; cf < 7; ++cf) {
        const int g = cf * 16 + l15;
        bias[cf] = (g < GG) ? Bias[n * GG + g] : 0.0f;
    }
    short8 areg[2][4];
    conv_x(raw, areg);

    __syncthreads();

    f32x4 acc[2][7];
    #pragma unroll
    for (int rf = 0; rf < 2; ++rf)
        #pragma unroll
        for (int cf = 0; cf < 7; ++cf)
            acc[rf][cf] = (f32x4){0.f, 0.f, 0.f, 0.f};

    #pragma unroll
    for (int cf = 0; cf < 7; ++cf) {
        const int g    = cf * 16 + l15;
        const int rowb = g * ROWB;
        const int swz  = (g & 7) << 4;
        #pragma unroll
        for (int ks = 0; ks < 4; ++ks) {
            const int off = rowb + (((lhi * 16) + ks * 64) ^ swz);
            const i32x4 braw = *reinterpret_cast<const i32x4*>(smem + off);
            const short8 bfrag = __builtin_bit_cast(short8, braw);
            acc[0][cf] = __builtin_amdgcn_mfma_f32_16x16x32_bf16(areg[0][ks], bfrag, acc[0][cf], 0, 0, 0);
            acc[1][cf] = __builtin_amdgcn_mfma_f32_16x16x32_bf16(areg[1][ks], bfrag, acc[1][cf], 0, 0, 0);
        }
    }

    __syncthreads();

    float* lds_f = reinterpret_cast<float*>(smem + wid * SCR);
    #pragma unroll
    for (int rf = 0; rf < 2; ++rf) {
        #pragma unroll
        for (int cf = 0; cf < 7; ++cf) {
            const int g = cf * 16 + l15;
            if (g < GG) {
                #pragma unroll
                for (int j = 0; j < 4; ++j)
                    lds_f[(lhi * 4 + j) * GG + g] = acc[rf][cf][j] + bias[cf];
            }
        }
        WAIT_LGKM0();
        const char* rgn = smem + wid * SCR;
        char* dst = (char*)(Out + ((size_t)n * BSZ + rowbase + rf * 16) * GG);
        #pragma unroll
        for (int it = 0; it < 7; ++it) {
            const int c = it * 64 + lane;
            if (c < 400) {
                const i32x4 v = *reinterpret_cast<const i32x4*>(rgn + c * 16);
                *reinterpret_cast<i32x4*>(dst + c * 16) = v;
            }
        }
        WAIT_LGKM0();
    }
}

extern "C" void kernel_launch(void* const* d_in, const int* in_sizes, int n_in,
                              void* d_out, int out_size, void* d_ws, size_t ws_size,
                              hipStream_t stream) {
    (void)in_sizes; (void)n_in; (void)out_size;
    const float* X    = (const float*)d_in[0];
    const float* W    = (const float*)d_in[1];
    const float* Bias = (const float*)d_in[2];
    float* Out        = (float*)d_out;
    const size_t wsneed = (size_t)NB * WIMG;   // 5,734,400 B
    if (ws_size >= wsneed) {
        wconv_kernel<<<(NB * WROWS * 16 + 255) / 256, 256, 0, stream>>>(W, (unsigned char*)d_ws);
        mtl_heads_bin<<<dim3(NBLK2), 256, 0, stream>>>(X, Bias, (const unsigned char*)d_ws, Out);
    } else {
        mtl_heads_fallback<<<dim3(16, NB), 256, 0, stream>>>(X, W, Bias, Out);
    }
}

// Round 8
// 95.900 us; speedup vs baseline: 1.0027x; 1.0027x over previous
//
#include <hip/hip_runtime.h>
#include <hip/hip_bf16.h>

// Problem constants (reference: B=2048, N_BINS=200, D=128, G=100)
#define NB    200
#define BSZ   2048
#define DD    128
#define GG    100
#define WROWS 112                 // padded gene rows (7 frags of 16) in WS image
#define ROWB  256                 // bytes per LDS W row (128 bf16)
#define WIMG  (WROWS * ROWB)      // 28672 B per-bin W image in d_ws
#define WLDS  (100 * ROWB)        // 25600 B staged rows (rows >=100 clamped)
#define SCR   6400                // per-wave epilogue scratch bytes
#define NBLK2 800                 // bin-major grid: block b -> bin b>>2, 4 mtiles

typedef __attribute__((ext_vector_type(8))) short  short8;  // 8 bf16 (MFMA A/B frag)
typedef __attribute__((ext_vector_type(4))) float  f32x4;   // MFMA C/D frag
typedef __attribute__((ext_vector_type(4))) int    i32x4;   // 16B chunk

// round-to-nearest-even f32 -> bf16, two at a time packed into a dword
__device__ __forceinline__ unsigned f2bf_pack(float lo, float hi) {
    unsigned ulo = __builtin_bit_cast(unsigned, lo);
    ulo += 0x7FFFu + ((ulo >> 16) & 1u);
    unsigned uhi = __builtin_bit_cast(unsigned, hi);
    uhi += 0x7FFFu + ((uhi >> 16) & 1u);
    return (ulo >> 16) | (uhi & 0xFFFF0000u);
}

__device__ __forceinline__ void gload_lds16(const void* g, void* l) {
    __builtin_amdgcn_global_load_lds(
        (const __attribute__((address_space(1))) unsigned int*)g,
        (__attribute__((address_space(3))) unsigned int*)l, 16, 0, 0);
}

// Wave-level LDS drain (scratch is wave-private): lgkmcnt(0) only.
#define WAIT_LGKM0() do { asm volatile("" ::: "memory");     \
                          __builtin_amdgcn_s_waitcnt(0xC07F);\
                          __builtin_amdgcn_sched_barrier(0); \
                          __builtin_amdgcn_wave_barrier();   \
                          asm volatile("" ::: "memory"); } while (0)

// Pin point: forbid the scheduler from moving anything across (in particular,
// from SINKING prefetch loads below the compute region — the round-7 bug:
// VGPR 84 < live-state 124 proved load_x was sunk to the loop bottom).
#define SCHED_PIN() do { __builtin_amdgcn_sched_barrier(0); \
                         asm volatile("" ::: "memory"); } while (0)

// ---------------------------------------------------------------------------
// Pre-pass: W f32 [NB][GG][DD] -> bf16 swizzled per-bin images in d_ws.
// byte off = row*256 + ((granule*16) ^ ((row&7)<<4)), rows >= GG zeroed.
// 16 granules of 16 B per row: 200*112*16 = 358400 threads.
// ---------------------------------------------------------------------------
__global__ __launch_bounds__(256) void wconv_kernel(
    const float* __restrict__ W, unsigned char* __restrict__ ws)
{
    const int gidx = blockIdx.x * 256 + threadIdx.x;
    if (gidx >= NB * WROWS * 16) return;
    const int gr  = gidx & 15;
    const int row = (gidx >> 4) % WROWS;
    const int n   = gidx / (WROWS * 16);
    i32x4 pack = (i32x4){0, 0, 0, 0};
    if (row < GG) {
        const float* src = W + ((size_t)n * GG + row) * DD + gr * 8;
        const f32x4 a = *reinterpret_cast<const f32x4*>(src);
        const f32x4 b = *reinterpret_cast<const f32x4*>(src + 4);
        pack.x = (int)f2bf_pack(a[0], a[1]);
        pack.y = (int)f2bf_pack(a[2], a[3]);
        pack.z = (int)f2bf_pack(b[0], b[1]);
        pack.w = (int)f2bf_pack(b[2], b[3]);
    }
    const int off = row * ROWB + ((gr * 16) ^ ((row & 7) << 4));
    *reinterpret_cast<i32x4*>(ws + (size_t)n * WIMG + off) = pack;
}

// ---------------------------------------------------------------------------
// Helpers
// ---------------------------------------------------------------------------
// Stage first 100 rows (25600 B) of bin n's image: 25 wave-chunks of 1024 B.
__device__ __forceinline__ void stage_w100(char* buf, const unsigned char* WS,
                                           int n, int lane, int wid) {
    const unsigned char* src = WS + (size_t)n * WIMG;
    #pragma unroll
    for (int i = 0; i < 6; ++i) {
        const int c = i * 4 + wid;                    // chunks 0..23
        gload_lds16(src + c * 1024 + lane * 16, buf + c * 1024);
    }
    if (wid == 0)                                     // chunk 24
        gload_lds16(src + 24 * 1024 + lane * 16, buf + 24 * 1024);
}

__device__ __forceinline__ void load_x(f32x4 (&raw)[2][4][2], const float* X,
                                       int n, int mtile, int wid, int l15, int lhi) {
    const int rowbase = mtile * 128 + wid * 32;
    #pragma unroll
    for (int rf = 0; rf < 2; ++rf) {
        const float* xrow = X + ((size_t)(rowbase + rf * 16 + l15) * NB + n) * DD + lhi * 8;
        #pragma unroll
        for (int ks = 0; ks < 4; ++ks) {
            raw[rf][ks][0] = *reinterpret_cast<const f32x4*>(xrow + ks * 32);
            raw[rf][ks][1] = *reinterpret_cast<const f32x4*>(xrow + ks * 32 + 4);
        }
    }
}

__device__ __forceinline__ void conv_x(const f32x4 (&raw)[2][4][2],
                                       short8 (&areg)[2][4]) {
    #pragma unroll
    for (int rf = 0; rf < 2; ++rf)
        #pragma unroll
        for (int ks = 0; ks < 4; ++ks) {
            const f32x4 a = raw[rf][ks][0];
            const f32x4 b = raw[rf][ks][1];
            i32x4 pk;
            pk.x = (int)f2bf_pack(a[0], a[1]);
            pk.y = (int)f2bf_pack(a[2], a[3]);
            pk.z = (int)f2bf_pack(b[0], b[1]);
            pk.w = (int)f2bf_pack(b[2], b[3]);
            areg[rf][ks] = __builtin_bit_cast(short8, pk);
        }
}

// ---------------------------------------------------------------------------
// Bin-major main kernel: block b -> bin n = b>>2, mtiles (b&3)*4 .. +3.
// W staged ONCE; 4-tile loop has NO cross-wave barriers. Prefetch loads are
// PINNED at the loop top with sched_barrier(0) so they overlap MFMA+epilogue
// (round-7 regression fix). conv_x at loop bottom gets a counted vmcnt wait
// (NT stores stay in flight).
// LDS = 25600 (W) + 4*6400 (scratch) = 51200 B -> 3 blocks/CU.
// ---------------------------------------------------------------------------
__global__ __launch_bounds__(256, 3) void mtl_heads_bin(
    const float* __restrict__ X, const float* __restrict__ Bias,
    const unsigned char* __restrict__ WS, float* __restrict__ Out)
{
    const int tid  = threadIdx.x;
    const int lane = tid & 63;
    const int wid  = tid >> 6;
    const int l15  = lane & 15;
    const int lhi  = lane >> 4;

    const int n   = blockIdx.x >> 2;
    const int mt0 = (blockIdx.x & 3) * 4;

    __shared__ __align__(16) char smem[WLDS + 4 * SCR];   // 51200 B

    // prologue: stage W[n] (async), issue first X tile — then PIN
    stage_w100(smem, WS, n, lane, wid);
    f32x4 raw[2][4][2];
    load_x(raw, X, n, mt0, wid, l15, lhi);
    SCHED_PIN();
    float bias[7];
    #pragma unroll
    for (int cf = 0; cf < 7; ++cf) {
        const int g = cf * 16 + l15;
        bias[cf] = (g < GG) ? Bias[n * GG + g] : 0.0f;
    }
    short8 areg[2][4];
    conv_x(raw, areg);          // counted vmcnt: X loads done (staging older, also done)
    __syncthreads();            // W visible to all waves; only barrier in kernel

    char* scratch = smem + WLDS + wid * SCR;

    for (int mt = 0; mt < 4; ++mt) {
        const int mtile = mt0 + mt;
        // 1. issue next tile's X loads and PIN them here (overlap MFMA+stores)
        if (mt < 3) {
            load_x(raw, X, n, mtile + 1, wid, l15, lhi);
        }
        SCHED_PIN();

        // 2. MFMA: 2 row-frags x 7 col-frags x 4 k-steps from read-only W LDS
        f32x4 acc[2][7];
        #pragma unroll
        for (int rf = 0; rf < 2; ++rf)
            #pragma unroll
            for (int cf = 0; cf < 7; ++cf)
                acc[rf][cf] = (f32x4){0.f, 0.f, 0.f, 0.f};

        #pragma unroll
        for (int cf = 0; cf < 7; ++cf) {
            const int g = cf * 16 + l15;
            const int r = (g < GG) ? g : 99;   // clamp: rows >=100 not staged; masked at store
            const int rowb = r * ROWB;
            const int swz  = (r & 7) << 4;
            #pragma unroll
            for (int ks = 0; ks < 4; ++ks) {
                const int off = rowb + (((lhi * 16) + ks * 64) ^ swz);
                const i32x4 braw = *reinterpret_cast<const i32x4*>(smem + off);  // ds_read_b128
                const short8 bfrag = __builtin_bit_cast(short8, braw);
                acc[0][cf] = __builtin_amdgcn_mfma_f32_16x16x32_bf16(areg[0][ks], bfrag, acc[0][cf], 0, 0, 0);
                acc[1][cf] = __builtin_amdgcn_mfma_f32_16x16x32_bf16(areg[1][ks], bfrag, acc[1][cf], 0, 0, 0);
            }
        }

        // 3. epilogue: wave-private transpose -> contiguous NT dwordx4 stores
        const int rowbase = mtile * 128 + wid * 32;
        float* lds_f = reinterpret_cast<float*>(scratch);
        #pragma unroll
        for (int rf = 0; rf < 2; ++rf) {
            #pragma unroll
            for (int cf = 0; cf < 7; ++cf) {
                const int g = cf * 16 + l15;
                if (g < GG) {
                    #pragma unroll
                    for (int j = 0; j < 4; ++j)
                        lds_f[(lhi * 4 + j) * GG + g] = acc[rf][cf][j] + bias[cf];
                }
            }
            WAIT_LGKM0();
            char* dst = (char*)(Out + ((size_t)n * BSZ + rowbase + rf * 16) * GG);
            #pragma unroll
            for (int it = 0; it < 7; ++it) {
                const int c = it * 64 + lane;        // 16B-chunk index, 400 total
                if (c < 400) {
                    const i32x4 v = *reinterpret_cast<const i32x4*>(scratch + c * 16);
                    __builtin_nontemporal_store(v, reinterpret_cast<i32x4*>(dst + c * 16));
                }
            }
            WAIT_LGKM0();   // scratch reads done before rf=1 (or next tile) overwrites
        }

        // 4. convert next tile's X (counted vmcnt; NT stores stay in flight)
        if (mt < 3) conv_x(raw, areg);
        SCHED_PIN();
    }
}

// ---------------------------------------------------------------------------
// Fallback (no workspace): single-tile kernel, in-kernel W convert.
// ---------------------------------------------------------------------------
__global__ __launch_bounds__(256, 4) void mtl_heads_fallback(
    const float* __restrict__ X, const float* __restrict__ W,
    const float* __restrict__ Bias, float* __restrict__ Out)
{
    const int n     = blockIdx.y;
    const int mtile = blockIdx.x;
    const int tid   = threadIdx.x;
    const int lane  = tid & 63;
    const int wid   = tid >> 6;
    const int l15   = lane & 15;
    const int lhi   = lane >> 4;

    __shared__ __align__(16) char smem[WIMG];

    {
        const int rsub = tid >> 4;
        const int k0   = (tid & 15) * 8;
        #pragma unroll
        for (int it = 0; it < 7; ++it) {
            const int row = it * 16 + rsub;
            i32x4 pack = (i32x4){0, 0, 0, 0};
            if (row < GG) {
                const float* s = W + ((size_t)n * GG + row) * DD + k0;
                const f32x4 a = *reinterpret_cast<const f32x4*>(s);
                const f32x4 b = *reinterpret_cast<const f32x4*>(s + 4);
                pack.x = (int)f2bf_pack(a[0], a[1]);
                pack.y = (int)f2bf_pack(a[2], a[3]);
                pack.z = (int)f2bf_pack(b[0], b[1]);
                pack.w = (int)f2bf_pack(b[2], b[3]);
            }
            const int off = row * ROWB + ((k0 * 2) ^ ((row & 7) << 4));
            *reinterpret_cast<i32x4*>(smem + off) = pack;
        }
    }

    const int rowbase = mtile * 128 + wid * 32;
    f32x4 raw[2][4][2];
    load_x(raw, X, n, mtile, wid, l15, lhi);
    float bias[7];
    #pragma unroll
    for (int cf = 0; cf < 7; ++cf) {
        const int g = cf * 16 + l15;
        bias[cf] = (g < GG) ? Bias[n * GG + g] : 0.0f;
    }
    short8 areg[2][4];
    conv_x(raw, areg);

    __syncthreads();

    f32x4 acc[2][7];
    #pragma unroll
    for (int rf = 0; rf < 2; ++rf)
        #pragma unroll
        for (int cf = 0; cf < 7; ++cf)
            acc[rf][cf] = (f32x4){0.f, 0.f, 0.f, 0.f};

    #pragma unroll
    for (int cf = 0; cf < 7; ++cf) {
        const int g    = cf * 16 + l15;
        const int rowb = g * ROWB;
        const int swz  = (g & 7) << 4;
        #pragma unroll
        for (int ks = 0; ks < 4; ++ks) {
            const int off = rowb + (((lhi * 16) + ks * 64) ^ swz);
            const i32x4 braw = *reinterpret_cast<const i32x4*>(smem + off);
            const short8 bfrag = __builtin_bit_cast(short8, braw);
            acc[0][cf] = __builtin_amdgcn_mfma_f32_16x16x32_bf16(areg[0][ks], bfrag, acc[0][cf], 0, 0, 0);
            acc[1][cf] = __builtin_amdgcn_mfma_f32_16x16x32_bf16(areg[1][ks], bfrag, acc[1][cf], 0, 0, 0);
        }
    }

    __syncthreads();

    float* lds_f = reinterpret_cast<float*>(smem + wid * SCR);
    #pragma unroll
    for (int rf = 0; rf < 2; ++rf) {
        #pragma unroll
        for (int cf = 0; cf < 7; ++cf) {
            const int g = cf * 16 + l15;
            if (g < GG) {
                #pragma unroll
                for (int j = 0; j < 4; ++j)
                    lds_f[(lhi * 4 + j) * GG + g] = acc[rf][cf][j] + bias[cf];
            }
        }
        WAIT_LGKM0();
        const char* rgn = smem + wid * SCR;
        char* dst = (char*)(Out + ((size_t)n * BSZ + rowbase + rf * 16) * GG);
        #pragma unroll
        for (int it = 0; it < 7; ++it) {
            const int c = it * 64 + lane;
            if (c < 400) {
                const i32x4 v = *reinterpret_cast<const i32x4*>(rgn + c * 16);
                *reinterpret_cast<i32x4*>(dst + c * 16) = v;
            }
        }
        WAIT_LGKM0();
    }
}

extern "C" void kernel_launch(void* const* d_in, const int* in_sizes, int n_in,
                              void* d_out, int out_size, void* d_ws, size_t ws_size,
                              hipStream_t stream) {
    (void)in_sizes; (void)n_in; (void)out_size;
    const float* X    = (const float*)d_in[0];
    const float* W    = (const float*)d_in[1];
    const float* Bias = (const float*)d_in[2];
    float* Out        = (float*)d_out;
    const size_t wsneed = (size_t)NB * WIMG;   // 5,734,400 B
    if (ws_size >= wsneed) {
        wconv_kernel<<<(NB * WROWS * 16 + 255) / 256, 256, 0, stream>>>(W, (unsigned char*)d_ws);
        mtl_heads_bin<<<dim3(NBLK2), 256, 0, stream>>>(X, Bias, (const unsigned char*)d_ws, Out);
    } else {
        mtl_heads_fallback<<<dim3(16, NB), 256, 0, stream>>>(X, W, Bias, Out);
    }
}